// Round 1
// baseline (1351.898 us; speedup 1.0000x reference)
//
#include <hip/hip_runtime.h>
#include <hip/hip_bf16.h>

#define NN 100000
#define NE 800000
#define NG 2000
#define EMB 64
#define HID 128
#define NCLS 10

// monotone float<->uint encoding so unsigned atomicMax == float max (handles negatives, -inf)
static __device__ __forceinline__ unsigned fenc(float f) {
    unsigned u = __float_as_uint(f);
    return (u & 0x80000000u) ? ~u : (u | 0x80000000u);
}
static __device__ __forceinline__ float fdec(unsigned u) {
    return (u & 0x80000000u) ? __uint_as_float(u & 0x7FFFFFFFu) : __uint_as_float(~u);
}

__global__ void k_init(int* degree, unsigned* genc, float* relp,
                       const float* rel_table, const float* w1_l) {
    int i = blockIdx.x * blockDim.x + threadIdx.x;
    if (i < NN) degree[i] = 0;
    if (i < NG * HID) genc[i] = 0x007FFFFFu;  // fenc(-inf)
    if (i < 3 * HID) {
        int t = i / HID, j = i % HID;
        float s = 0.f;
        for (int k = 0; k < 16; ++k)
            s += rel_table[t * 16 + k] * w1_l[(EMB + k) * HID + j];
        relp[i] = s;
    }
}

__global__ void k_embed(const int* tok, const float* emb, float* x) {
    int i = blockIdx.x * blockDim.x + threadIdx.x;  // over NN*EMB
    int n = i >> 6, f = i & 63;
    x[i] = emb[tok[n] * EMB + f];
}

__global__ void k_degree(const int* dst, int* degree) {
    int e = blockIdx.x * blockDim.x + threadIdx.x;
    if (e < NE) atomicAdd(&degree[dst[e]], 1);
}

// single-block exclusive scan of degree -> offsets (and cursor copy)
__global__ void k_scan(const int* degree, int* offsets, int* cursor) {
    __shared__ int sums[1024];
    int t = threadIdx.x;
    const int chunk = (NN + 1023) / 1024;
    int start = t * chunk;
    int end = min(start + chunk, NN);
    int s = 0;
    for (int i = start; i < end; ++i) s += degree[i];
    sums[t] = s;
    __syncthreads();
    for (int off = 1; off < 1024; off <<= 1) {
        int v = (t >= off) ? sums[t - off] : 0;
        __syncthreads();
        sums[t] += v;
        __syncthreads();
    }
    int run = (t == 0) ? 0 : sums[t - 1];
    for (int i = start; i < end; ++i) {
        offsets[i] = run;
        cursor[i] = run;
        run += degree[i];
    }
    if (t == 1023) offsets[NN] = sums[1023];
}

__global__ void k_bucket(const int* src, const int* dst, const int* etype,
                         int* cursor, int* packed) {
    int e = blockIdx.x * blockDim.x + threadIdx.x;
    if (e < NE) {
        int d = dst[e];
        int pos = atomicAdd(&cursor[d], 1);
        packed[pos] = src[e] | (etype[e] << 20);  // src < 2^17, type in bits 20..21
    }
}

// Layer 1 fused: per-wave aggregate mean(x[src]) + type counts, then
// h = relu(mean_x@w1_l[0:64] + (cnt . relp)/deg + x@w1_r + b1)
__global__ __launch_bounds__(256) void k_layer1(
    const int* __restrict__ offsets, const int* __restrict__ packed,
    const float* __restrict__ x,
    const float* __restrict__ w1_l, const float* __restrict__ w1_r,
    const float* __restrict__ b1, const float* __restrict__ relp,
    float* __restrict__ h) {
    __shared__ float s_w1x[EMB * HID];   // 32 KB (first 64 rows of w1_l)
    __shared__ float s_w1r[EMB * HID];   // 32 KB
    __shared__ float s_relp[3 * HID];
    __shared__ float s_b1[HID];
    __shared__ float s_mean[4][EMB];
    __shared__ float s_xrow[4][EMB];

    int tid = threadIdx.x;
    for (int i = tid; i < EMB * HID; i += 256) {
        s_w1x[i] = w1_l[i];
        s_w1r[i] = w1_r[i];
    }
    for (int i = tid; i < 3 * HID; i += 256) s_relp[i] = relp[i];
    if (tid < HID) s_b1[tid] = b1[tid];
    __syncthreads();

    int wid = tid >> 6, lane = tid & 63;
    int base = blockIdx.x * 16 + wid * 4;   // 6250 * 16 == NN exactly
    for (int it = 0; it < 4; ++it) {
        int node = base + it;
        int beg = offsets[node], endo = offsets[node + 1];
        float acc = 0.f;
        int c0 = 0, c1 = 0, c2 = 0;
        for (int e = beg; e < endo; ++e) {
            int val = packed[e];
            int s = val & 0xFFFFF;
            int t = val >> 20;
            acc += x[s * EMB + lane];
            c0 += (t == 0); c1 += (t == 1); c2 += (t == 2);
        }
        int deg = endo - beg;
        float inv = 1.0f / (float)max(deg, 1);
        s_mean[wid][lane] = acc * inv;
        s_xrow[wid][lane] = x[node * EMB + lane];
        __syncthreads();
        int j0 = lane * 2;
        float fc0 = (float)c0 * inv, fc1 = (float)c1 * inv, fc2 = (float)c2 * inv;
        float o0 = s_b1[j0]     + fc0 * s_relp[j0]     + fc1 * s_relp[HID + j0]     + fc2 * s_relp[2 * HID + j0];
        float o1 = s_b1[j0 + 1] + fc0 * s_relp[j0 + 1] + fc1 * s_relp[HID + j0 + 1] + fc2 * s_relp[2 * HID + j0 + 1];
        #pragma unroll 8
        for (int k = 0; k < EMB; ++k) {
            float mk = s_mean[wid][k];
            float xk = s_xrow[wid][k];
            float2 wx = *(const float2*)&s_w1x[k * HID + j0];
            float2 wr = *(const float2*)&s_w1r[k * HID + j0];
            o0 += mk * wx.x + xk * wr.x;
            o1 += mk * wx.y + xk * wr.y;
        }
        float2 out2 = make_float2(fmaxf(o0, 0.f), fmaxf(o1, 0.f));
        *(float2*)&h[node * HID + j0] = out2;
        __syncthreads();
    }
}

// Layer 2 fused + pooling: h2 = mean(h[src])@w2_l + h@w2_r + b2; atomicMax into genc[batch]
__global__ __launch_bounds__(512) void k_layer2(
    const int* __restrict__ offsets, const int* __restrict__ packed,
    const float* __restrict__ h,
    const float* __restrict__ w2_l, const float* __restrict__ w2_r,
    const float* __restrict__ b2, const int* __restrict__ batch,
    unsigned* __restrict__ genc) {
    __shared__ float s_wl[HID * HID];   // 64 KB
    __shared__ float s_wr[HID * HID];   // 64 KB
    __shared__ float s_b2[HID];
    __shared__ float s_mean[8][HID];
    __shared__ float s_hrow[8][HID];

    int tid = threadIdx.x;
    for (int i = tid; i < HID * HID; i += 512) {
        s_wl[i] = w2_l[i];
        s_wr[i] = w2_r[i];
    }
    if (tid < HID) s_b2[tid] = b2[tid];
    __syncthreads();

    int wid = tid >> 6, lane = tid & 63;
    int base = blockIdx.x * 32 + wid * 4;   // 3125 * 32 == NN exactly
    for (int it = 0; it < 4; ++it) {
        int node = base + it;
        int beg = offsets[node], endo = offsets[node + 1];
        float a0 = 0.f, a1 = 0.f;
        for (int e = beg; e < endo; ++e) {
            int s = packed[e] & 0xFFFFF;
            a0 += h[s * HID + lane];
            a1 += h[s * HID + 64 + lane];
        }
        float inv = 1.0f / (float)max(endo - beg, 1);
        s_mean[wid][lane] = a0 * inv;
        s_mean[wid][lane + 64] = a1 * inv;
        s_hrow[wid][lane] = h[node * HID + lane];
        s_hrow[wid][lane + 64] = h[node * HID + 64 + lane];
        __syncthreads();
        int j0 = lane * 2;
        float o0a = 0.f, o0b = 0.f, o1a = 0.f, o1b = 0.f;
        #pragma unroll 4
        for (int k = 0; k < HID; k += 2) {
            float mk0 = s_mean[wid][k], hk0 = s_hrow[wid][k];
            float2 wl0 = *(const float2*)&s_wl[k * HID + j0];
            float2 wr0 = *(const float2*)&s_wr[k * HID + j0];
            o0a += mk0 * wl0.x + hk0 * wr0.x;
            o1a += mk0 * wl0.y + hk0 * wr0.y;
            float mk1 = s_mean[wid][k + 1], hk1 = s_hrow[wid][k + 1];
            float2 wl1 = *(const float2*)&s_wl[(k + 1) * HID + j0];
            float2 wr1 = *(const float2*)&s_wr[(k + 1) * HID + j0];
            o0b += mk1 * wl1.x + hk1 * wr1.x;
            o1b += mk1 * wl1.y + hk1 * wr1.y;
        }
        float o0 = s_b2[j0] + o0a + o0b;
        float o1 = s_b2[j0 + 1] + o1a + o1b;
        int b = batch[node];
        atomicMax(&genc[b * HID + j0], fenc(o0));
        atomicMax(&genc[b * HID + j0 + 1], fenc(o1));
        __syncthreads();
    }
}

// decode pooled max, relu, project to classes
__global__ void k_final(const unsigned* __restrict__ genc,
                        const float* __restrict__ lin_w, const float* __restrict__ lin_b,
                        float* __restrict__ out) {
    int gr = blockIdx.x;
    int lane = threadIdx.x;  // 64
    float g0 = fmaxf(fdec(genc[gr * HID + lane]), 0.f);
    float g1 = fmaxf(fdec(genc[gr * HID + 64 + lane]), 0.f);
    #pragma unroll
    for (int c = 0; c < NCLS; ++c) {
        float p = g0 * lin_w[lane * NCLS + c] + g1 * lin_w[(lane + 64) * NCLS + c];
        for (int off = 32; off > 0; off >>= 1)
            p += __shfl_down(p, off, 64);
        if (lane == 0) out[gr * NCLS + c] = p + lin_b[c];
    }
}

extern "C" void kernel_launch(void* const* d_in, const int* in_sizes, int n_in,
                              void* d_out, int out_size, void* d_ws, size_t ws_size,
                              hipStream_t stream) {
    const int* x_tokens   = (const int*)d_in[0];
    const int* edge_index = (const int*)d_in[1];
    const int* edge_type  = (const int*)d_in[2];
    const int* batch      = (const int*)d_in[3];
    const float* emb_table = (const float*)d_in[5];
    const float* rel_table = (const float*)d_in[6];
    const float* w1_l = (const float*)d_in[7];
    const float* b1   = (const float*)d_in[8];
    const float* w1_r = (const float*)d_in[9];
    const float* w2_l = (const float*)d_in[10];
    const float* b2   = (const float*)d_in[11];
    const float* w2_r = (const float*)d_in[12];
    const float* lin_w = (const float*)d_in[13];
    const float* lin_b = (const float*)d_in[14];
    float* out = (float*)d_out;

    const int* src = edge_index;
    const int* dst = edge_index + NE;

    char* ws = (char*)d_ws;
    size_t off = 0;
    auto alloc = [&](size_t bytes) {
        void* p = ws + off;
        off = (off + bytes + 255) & ~(size_t)255;
        return p;
    };
    float* x        = (float*)alloc((size_t)NN * EMB * 4);   // 25.6 MB
    float* h        = (float*)alloc((size_t)NN * HID * 4);   // 51.2 MB
    int* degree     = (int*)alloc((size_t)NN * 4);
    int* offsets    = (int*)alloc((size_t)(NN + 1) * 4);
    int* cursor     = (int*)alloc((size_t)NN * 4);
    int* packed     = (int*)alloc((size_t)NE * 4);           // 3.2 MB
    unsigned* genc  = (unsigned*)alloc((size_t)NG * HID * 4);
    float* relp     = (float*)alloc((size_t)3 * HID * 4);
    (void)ws_size; (void)in_sizes; (void)n_in; (void)out_size;

    hipLaunchKernelGGL(k_init,   dim3((NG * HID + 255) / 256), dim3(256), 0, stream,
                       degree, genc, relp, rel_table, w1_l);
    hipLaunchKernelGGL(k_embed,  dim3(NN * EMB / 256), dim3(256), 0, stream,
                       x_tokens, emb_table, x);
    hipLaunchKernelGGL(k_degree, dim3((NE + 255) / 256), dim3(256), 0, stream, dst, degree);
    hipLaunchKernelGGL(k_scan,   dim3(1), dim3(1024), 0, stream, degree, offsets, cursor);
    hipLaunchKernelGGL(k_bucket, dim3((NE + 255) / 256), dim3(256), 0, stream,
                       src, dst, edge_type, cursor, packed);
    hipLaunchKernelGGL(k_layer1, dim3(NN / 16), dim3(256), 0, stream,
                       offsets, packed, x, w1_l, w1_r, b1, relp, h);
    hipLaunchKernelGGL(k_layer2, dim3(NN / 32), dim3(512), 0, stream,
                       offsets, packed, h, w2_l, w2_r, b2, batch, genc);
    hipLaunchKernelGGL(k_final,  dim3(NG), dim3(64), 0, stream, genc, lin_w, lin_b, out);
}

// Round 2
// 606.257 us; speedup vs baseline: 2.2299x; 2.2299x over previous
//
#include <hip/hip_runtime.h>
#include <hip/hip_bf16.h>

#define NN 100000
#define NE 800000
#define NG 2000
#define EMB 64
#define HID 128
#define NCLS 10

// monotone float<->uint encoding so unsigned atomicMax == float max
static __device__ __forceinline__ unsigned fenc(float f) {
    unsigned u = __float_as_uint(f);
    return (u & 0x80000000u) ? ~u : (u | 0x80000000u);
}
static __device__ __forceinline__ float fdec(unsigned u) {
    return (u & 0x80000000u) ? __uint_as_float(u & 0x7FFFFFFFu) : __uint_as_float(~u);
}

__global__ void k_init(int* degree, unsigned* genc, float* relp,
                       const float* rel_table, const float* w1_l) {
    int i = blockIdx.x * blockDim.x + threadIdx.x;
    if (i < NN) degree[i] = 0;
    if (i < NG * HID) genc[i] = 0x007FFFFFu;  // fenc(-inf)
    if (i < 3 * HID) {
        int t = i / HID, j = i % HID;
        float s = 0.f;
        for (int k = 0; k < 16; ++k)
            s += rel_table[t * 16 + k] * w1_l[(EMB + k) * HID + j];
        relp[i] = s;
    }
}

__global__ void k_embed(const int* tok, const float* emb, float* x) {
    int i = blockIdx.x * blockDim.x + threadIdx.x;  // over NN*EMB
    int n = i >> 6, f = i & 63;
    x[i] = emb[tok[n] * EMB + f];
}

__global__ void k_degree(const int* dst, int* degree) {
    int e = blockIdx.x * blockDim.x + threadIdx.x;
    if (e < NE) atomicAdd(&degree[dst[e]], 1);
}

__global__ void k_scan(const int* degree, int* offsets, int* cursor) {
    __shared__ int sums[1024];
    int t = threadIdx.x;
    const int chunk = (NN + 1023) / 1024;
    int start = t * chunk;
    int end = min(start + chunk, NN);
    int s = 0;
    for (int i = start; i < end; ++i) s += degree[i];
    sums[t] = s;
    __syncthreads();
    for (int off = 1; off < 1024; off <<= 1) {
        int v = (t >= off) ? sums[t - off] : 0;
        __syncthreads();
        sums[t] += v;
        __syncthreads();
    }
    int run = (t == 0) ? 0 : sums[t - 1];
    for (int i = start; i < end; ++i) {
        offsets[i] = run;
        cursor[i] = run;
        run += degree[i];
    }
    if (t == 1023) offsets[NN] = sums[1023];
}

__global__ void k_bucket(const int* src, const int* dst, const int* etype,
                         int* cursor, int* packed) {
    int e = blockIdx.x * blockDim.x + threadIdx.x;
    if (e < NE) {
        int d = dst[e];
        int pos = atomicAdd(&cursor[d], 1);
        packed[pos] = src[e] | (etype[e] << 20);
    }
}

// gather: mean of x[src] (64f) + relation-type fractions. One wave per node.
__global__ __launch_bounds__(256) void k_agg1(
    const int* __restrict__ offsets, const int* __restrict__ packed,
    const float* __restrict__ x, float* __restrict__ aggx, float* __restrict__ fc) {
    int node = (blockIdx.x * 256 + threadIdx.x) >> 6;
    int lane = threadIdx.x & 63;
    int beg = offsets[node], end = offsets[node + 1];
    float s0 = 0.f, s1 = 0.f, s2 = 0.f, s3 = 0.f;
    int c0 = 0, c1 = 0, c2 = 0;
    int e = beg;
    for (; e + 4 <= end; e += 4) {
        int p0 = packed[e], p1 = packed[e + 1], p2 = packed[e + 2], p3 = packed[e + 3];
        s0 += x[(p0 & 0xFFFFF) * EMB + lane];
        s1 += x[(p1 & 0xFFFFF) * EMB + lane];
        s2 += x[(p2 & 0xFFFFF) * EMB + lane];
        s3 += x[(p3 & 0xFFFFF) * EMB + lane];
        int t0 = p0 >> 20, t1 = p1 >> 20, t2 = p2 >> 20, t3 = p3 >> 20;
        c0 += (t0 == 0) + (t1 == 0) + (t2 == 0) + (t3 == 0);
        c1 += (t0 == 1) + (t1 == 1) + (t2 == 1) + (t3 == 1);
        c2 += (t0 == 2) + (t1 == 2) + (t2 == 2) + (t3 == 2);
    }
    for (; e < end; ++e) {
        int p = packed[e];
        s0 += x[(p & 0xFFFFF) * EMB + lane];
        int t = p >> 20;
        c0 += (t == 0); c1 += (t == 1); c2 += (t == 2);
    }
    float inv = 1.0f / (float)max(end - beg, 1);
    aggx[node * EMB + lane] = (s0 + s1 + s2 + s3) * inv;
    if (lane == 0)
        *(float4*)&fc[node * 4] = make_float4(c0 * inv, c1 * inv, c2 * inv, 0.f);
}

// gather: mean of h[src] (128f). One wave per node, 2 feats/lane, unroll 2 edges.
__global__ __launch_bounds__(256) void k_agg2(
    const int* __restrict__ offsets, const int* __restrict__ packed,
    const float* __restrict__ h, float* __restrict__ aggh) {
    int node = (blockIdx.x * 256 + threadIdx.x) >> 6;
    int lane = threadIdx.x & 63;
    int beg = offsets[node], end = offsets[node + 1];
    float a0 = 0.f, a1 = 0.f, b0 = 0.f, b1 = 0.f;
    int e = beg;
    for (; e + 2 <= end; e += 2) {
        int p0 = packed[e], p1 = packed[e + 1];
        const float* r0 = &h[(p0 & 0xFFFFF) * HID];
        const float* r1 = &h[(p1 & 0xFFFFF) * HID];
        a0 += r0[lane]; a1 += r0[lane + 64];
        b0 += r1[lane]; b1 += r1[lane + 64];
    }
    if (e < end) {
        const float* r0 = &h[(packed[e] & 0xFFFFF) * HID];
        a0 += r0[lane]; a1 += r0[lane + 64];
    }
    float inv = 1.0f / (float)max(end - beg, 1);
    aggh[node * HID + lane] = (a0 + b0) * inv;
    aggh[node * HID + 64 + lane] = (a1 + b1) * inv;
}

// register-tiled GEMM layer1: C[64m x 128n] per block, K=128 ([aggx|x] @ [w1x;w1r])
// epilogue: + b1 + fc.relp, relu -> h
__global__ __launch_bounds__(256) void k_gemm1(
    const float* __restrict__ aggx, const float* __restrict__ x,
    const float* __restrict__ fc,
    const float* __restrict__ w1l, const float* __restrict__ w1r,
    const float* __restrict__ b1, const float* __restrict__ relp,
    float* __restrict__ h) {
    __shared__ float As[32][65];
    __shared__ float Bs[32][132];
    __shared__ float s_epi[512];  // [0:128)=b1, [128:512)=relp rows 0..2
    int tid = threadIdx.x;
    int mbase = blockIdx.x * 64;
    for (int i = tid; i < 512; i += 256)
        s_epi[i] = (i < 128) ? b1[i] : relp[i - 128];
    float acc[4][8];
    #pragma unroll
    for (int i = 0; i < 4; ++i)
        #pragma unroll
        for (int j = 0; j < 8; ++j) acc[i][j] = 0.f;
    const int m0 = (tid >> 4) * 4;
    const int n0 = (tid & 15) * 4;
    const int aln = tid >> 2;           // local node 0..63
    const int akk = (tid & 3) * 8;      // k-offset within step
    const int anode = min(mbase + aln, NN - 1);
    const int br = tid >> 3;            // B row 0..31
    const int bc = (tid & 7) * 16;      // B col
    #pragma unroll
    for (int step = 0; step < 4; ++step) {
        const int k0 = step * 32;
        const float* ap = (k0 < 64) ? &aggx[anode * EMB + k0 + akk]
                                    : &x[anode * EMB + (k0 - 64) + akk];
        float4 av0 = *(const float4*)ap;
        float4 av1 = *(const float4*)(ap + 4);
        const int gr = k0 + br;
        const float* bp = (gr < 64) ? &w1l[gr * HID + bc] : &w1r[(gr - 64) * HID + bc];
        float4 bv0 = *(const float4*)bp;
        float4 bv1 = *(const float4*)(bp + 4);
        float4 bv2 = *(const float4*)(bp + 8);
        float4 bv3 = *(const float4*)(bp + 12);
        __syncthreads();
        As[akk + 0][aln] = av0.x; As[akk + 1][aln] = av0.y;
        As[akk + 2][aln] = av0.z; As[akk + 3][aln] = av0.w;
        As[akk + 4][aln] = av1.x; As[akk + 5][aln] = av1.y;
        As[akk + 6][aln] = av1.z; As[akk + 7][aln] = av1.w;
        *(float4*)&Bs[br][bc] = bv0;
        *(float4*)&Bs[br][bc + 4] = bv1;
        *(float4*)&Bs[br][bc + 8] = bv2;
        *(float4*)&Bs[br][bc + 12] = bv3;
        __syncthreads();
        #pragma unroll 8
        for (int kk = 0; kk < 32; ++kk) {
            float4 a = *(const float4*)&As[kk][m0];
            float4 bl = *(const float4*)&Bs[kk][n0];
            float4 bh = *(const float4*)&Bs[kk][n0 + 64];
            float am[4] = {a.x, a.y, a.z, a.w};
            float bb[8] = {bl.x, bl.y, bl.z, bl.w, bh.x, bh.y, bh.z, bh.w};
            #pragma unroll
            for (int mi = 0; mi < 4; ++mi)
                #pragma unroll
                for (int ni = 0; ni < 8; ++ni)
                    acc[mi][ni] += am[mi] * bb[ni];
        }
    }
    #pragma unroll
    for (int mi = 0; mi < 4; ++mi) {
        int node = mbase + m0 + mi;
        if (node >= NN) continue;
        float4 f = *(const float4*)&fc[node * 4];
        float o[8];
        #pragma unroll
        for (int ni = 0; ni < 8; ++ni) {
            int c = (ni < 4) ? (n0 + ni) : (n0 + 60 + ni);
            float v = acc[mi][ni] + s_epi[c]
                    + f.x * s_epi[128 + c] + f.y * s_epi[256 + c] + f.z * s_epi[384 + c];
            o[ni] = fmaxf(v, 0.f);
        }
        *(float4*)&h[node * HID + n0] = make_float4(o[0], o[1], o[2], o[3]);
        *(float4*)&h[node * HID + n0 + 64] = make_float4(o[4], o[5], o[6], o[7]);
    }
}

// register-tiled GEMM layer2: K=256 ([aggh|h] @ [w2l;w2r]), epilogue: +b2, pooled atomicMax
__global__ __launch_bounds__(256) void k_gemm2(
    const float* __restrict__ aggh, const float* __restrict__ h,
    const float* __restrict__ w2l, const float* __restrict__ w2r,
    const float* __restrict__ b2, const int* __restrict__ batch,
    unsigned* __restrict__ genc) {
    __shared__ float As[32][65];
    __shared__ float Bs[32][132];
    __shared__ float s_b2[128];
    int tid = threadIdx.x;
    int mbase = blockIdx.x * 64;
    if (tid < 128) s_b2[tid] = b2[tid];
    float acc[4][8];
    #pragma unroll
    for (int i = 0; i < 4; ++i)
        #pragma unroll
        for (int j = 0; j < 8; ++j) acc[i][j] = 0.f;
    const int m0 = (tid >> 4) * 4;
    const int n0 = (tid & 15) * 4;
    const int aln = tid >> 2;
    const int akk = (tid & 3) * 8;
    const int anode = min(mbase + aln, NN - 1);
    const int br = tid >> 3;
    const int bc = (tid & 7) * 16;
    #pragma unroll
    for (int step = 0; step < 8; ++step) {
        const int k0 = step * 32;
        const float* ap = (k0 < 128) ? &aggh[anode * HID + k0 + akk]
                                     : &h[anode * HID + (k0 - 128) + akk];
        float4 av0 = *(const float4*)ap;
        float4 av1 = *(const float4*)(ap + 4);
        const int gr = k0 + br;
        const float* bp = (gr < 128) ? &w2l[gr * HID + bc] : &w2r[(gr - 128) * HID + bc];
        float4 bv0 = *(const float4*)bp;
        float4 bv1 = *(const float4*)(bp + 4);
        float4 bv2 = *(const float4*)(bp + 8);
        float4 bv3 = *(const float4*)(bp + 12);
        __syncthreads();
        As[akk + 0][aln] = av0.x; As[akk + 1][aln] = av0.y;
        As[akk + 2][aln] = av0.z; As[akk + 3][aln] = av0.w;
        As[akk + 4][aln] = av1.x; As[akk + 5][aln] = av1.y;
        As[akk + 6][aln] = av1.z; As[akk + 7][aln] = av1.w;
        *(float4*)&Bs[br][bc] = bv0;
        *(float4*)&Bs[br][bc + 4] = bv1;
        *(float4*)&Bs[br][bc + 8] = bv2;
        *(float4*)&Bs[br][bc + 12] = bv3;
        __syncthreads();
        #pragma unroll 8
        for (int kk = 0; kk < 32; ++kk) {
            float4 a = *(const float4*)&As[kk][m0];
            float4 bl = *(const float4*)&Bs[kk][n0];
            float4 bh = *(const float4*)&Bs[kk][n0 + 64];
            float am[4] = {a.x, a.y, a.z, a.w};
            float bb[8] = {bl.x, bl.y, bl.z, bl.w, bh.x, bh.y, bh.z, bh.w};
            #pragma unroll
            for (int mi = 0; mi < 4; ++mi)
                #pragma unroll
                for (int ni = 0; ni < 8; ++ni)
                    acc[mi][ni] += am[mi] * bb[ni];
        }
    }
    int nd[4], bt[4];
    bool allok = true;
    #pragma unroll
    for (int mi = 0; mi < 4; ++mi) {
        nd[mi] = mbase + m0 + mi;
        bool ok = nd[mi] < NN;
        allok = allok && ok;
        bt[mi] = ok ? batch[nd[mi]] : -1;
    }
    bool same = allok && (bt[0] == bt[1]) && (bt[1] == bt[2]) && (bt[2] == bt[3]);
    if (same) {
        #pragma unroll
        for (int ni = 0; ni < 8; ++ni) {
            int c = (ni < 4) ? (n0 + ni) : (n0 + 60 + ni);
            float v = fmaxf(fmaxf(acc[0][ni], acc[1][ni]), fmaxf(acc[2][ni], acc[3][ni]));
            atomicMax(&genc[bt[0] * HID + c], fenc(v + s_b2[c]));
        }
    } else {
        #pragma unroll
        for (int mi = 0; mi < 4; ++mi) {
            if (nd[mi] >= NN) continue;
            #pragma unroll
            for (int ni = 0; ni < 8; ++ni) {
                int c = (ni < 4) ? (n0 + ni) : (n0 + 60 + ni);
                atomicMax(&genc[bt[mi] * HID + c], fenc(acc[mi][ni] + s_b2[c]));
            }
        }
    }
}

__global__ void k_final(const unsigned* __restrict__ genc,
                        const float* __restrict__ lin_w, const float* __restrict__ lin_b,
                        float* __restrict__ out) {
    int gr = blockIdx.x;
    int lane = threadIdx.x;  // 64
    float g0 = fmaxf(fdec(genc[gr * HID + lane]), 0.f);
    float g1 = fmaxf(fdec(genc[gr * HID + 64 + lane]), 0.f);
    #pragma unroll
    for (int c = 0; c < NCLS; ++c) {
        float p = g0 * lin_w[lane * NCLS + c] + g1 * lin_w[(lane + 64) * NCLS + c];
        for (int off = 32; off > 0; off >>= 1)
            p += __shfl_down(p, off, 64);
        if (lane == 0) out[gr * NCLS + c] = p + lin_b[c];
    }
}

extern "C" void kernel_launch(void* const* d_in, const int* in_sizes, int n_in,
                              void* d_out, int out_size, void* d_ws, size_t ws_size,
                              hipStream_t stream) {
    const int* x_tokens   = (const int*)d_in[0];
    const int* edge_index = (const int*)d_in[1];
    const int* edge_type  = (const int*)d_in[2];
    const int* batch      = (const int*)d_in[3];
    const float* emb_table = (const float*)d_in[5];
    const float* rel_table = (const float*)d_in[6];
    const float* w1_l = (const float*)d_in[7];
    const float* b1   = (const float*)d_in[8];
    const float* w1_r = (const float*)d_in[9];
    const float* w2_l = (const float*)d_in[10];
    const float* b2   = (const float*)d_in[11];
    const float* w2_r = (const float*)d_in[12];
    const float* lin_w = (const float*)d_in[13];
    const float* lin_b = (const float*)d_in[14];
    float* out = (float*)d_out;

    const int* src = edge_index;
    const int* dst = edge_index + NE;

    char* ws = (char*)d_ws;
    size_t off = 0;
    auto alloc = [&](size_t bytes) {
        void* p = ws + off;
        off = (off + bytes + 255) & ~(size_t)255;
        return p;
    };
    // region0 holds x|aggx during layer1, then is reused as aggh for layer2
    float* region0 = (float*)alloc((size_t)NN * HID * 4);   // 51.2 MB
    float* x    = region0;
    float* aggx = region0 + (size_t)NN * EMB;
    float* aggh = region0;
    float* h    = (float*)alloc((size_t)NN * HID * 4);      // 51.2 MB
    float* fc   = (float*)alloc((size_t)NN * 4 * 4);
    int* degree  = (int*)alloc((size_t)NN * 4);
    int* offsets = (int*)alloc((size_t)(NN + 1) * 4);
    int* cursor  = (int*)alloc((size_t)NN * 4);
    int* packed  = (int*)alloc((size_t)NE * 4);
    unsigned* genc = (unsigned*)alloc((size_t)NG * HID * 4);
    float* relp  = (float*)alloc((size_t)3 * HID * 4);
    (void)ws_size; (void)in_sizes; (void)n_in; (void)out_size;

    const int MT = (NN + 63) / 64;  // 1563 GEMM m-tiles

    hipLaunchKernelGGL(k_init,   dim3((NG * HID + 255) / 256), dim3(256), 0, stream,
                       degree, genc, relp, rel_table, w1_l);
    hipLaunchKernelGGL(k_embed,  dim3(NN * EMB / 256), dim3(256), 0, stream,
                       x_tokens, emb_table, x);
    hipLaunchKernelGGL(k_degree, dim3((NE + 255) / 256), dim3(256), 0, stream, dst, degree);
    hipLaunchKernelGGL(k_scan,   dim3(1), dim3(1024), 0, stream, degree, offsets, cursor);
    hipLaunchKernelGGL(k_bucket, dim3((NE + 255) / 256), dim3(256), 0, stream,
                       src, dst, edge_type, cursor, packed);
    hipLaunchKernelGGL(k_agg1,   dim3(NN / 4), dim3(256), 0, stream,
                       offsets, packed, x, aggx, fc);
    hipLaunchKernelGGL(k_gemm1,  dim3(MT), dim3(256), 0, stream,
                       aggx, x, fc, w1_l, w1_r, b1, relp, h);
    hipLaunchKernelGGL(k_agg2,   dim3(NN / 4), dim3(256), 0, stream,
                       offsets, packed, h, aggh);
    hipLaunchKernelGGL(k_gemm2,  dim3(MT), dim3(256), 0, stream,
                       aggh, h, w2_l, w2_r, b2, batch, genc);
    hipLaunchKernelGGL(k_final,  dim3(NG), dim3(64), 0, stream, genc, lin_w, lin_b, out);
}

// Round 3
// 398.551 us; speedup vs baseline: 3.3920x; 1.5212x over previous
//
#include <hip/hip_runtime.h>
#include <hip/hip_bf16.h>

#define NN 100000
#define NE 800000
#define NG 2000
#define EMB 64
#define HID 128
#define NCLS 10
#define SCHUNK 512
#define NSB ((NN + SCHUNK - 1) / SCHUNK)   // 196 scan blocks

// monotone float<->uint encoding so unsigned atomicMax == float max
static __device__ __forceinline__ unsigned fenc(float f) {
    unsigned u = __float_as_uint(f);
    return (u & 0x80000000u) ? ~u : (u | 0x80000000u);
}
static __device__ __forceinline__ float fdec(unsigned u) {
    return (u & 0x80000000u) ? __uint_as_float(u & 0x7FFFFFFFu) : __uint_as_float(~u);
}

__global__ void k_init(int* degree, unsigned* genc, float* relp,
                       const float* rel_table, const float* w1_l) {
    int i = blockIdx.x * blockDim.x + threadIdx.x;
    if (i < NN) degree[i] = 0;
    if (i < NG * HID) genc[i] = 0x007FFFFFu;  // fenc(-inf)
    if (i < 3 * HID) {
        int t = i / HID, j = i % HID;
        float s = 0.f;
        for (int k = 0; k < 16; ++k)
            s += rel_table[t * 16 + k] * w1_l[(EMB + k) * HID + j];
        relp[i] = s;
    }
}

__global__ void k_embed(const int* tok, const float* emb, float* x) {
    int i = blockIdx.x * blockDim.x + threadIdx.x;  // over NN*EMB
    int n = i >> 6, f = i & 63;
    x[i] = emb[tok[n] * EMB + f];
}

__global__ void k_degree(const int* dst, int* degree) {
    int e = blockIdx.x * blockDim.x + threadIdx.x;
    if (e < NE) atomicAdd(&degree[dst[e]], 1);
}

// scan phase 1: per-block (512-node chunk) degree sums
__global__ __launch_bounds__(256) void k_scan1(const int* __restrict__ degree,
                                               int* __restrict__ partial) {
    __shared__ int ws[4];
    int t = threadIdx.x;
    int i0 = blockIdx.x * SCHUNK + t * 2;
    int e0 = (i0 < NN) ? degree[i0] : 0;
    int e1 = (i0 + 1 < NN) ? degree[i0 + 1] : 0;
    int s = e0 + e1;
    for (int off = 32; off > 0; off >>= 1) s += __shfl_down(s, off, 64);
    if ((t & 63) == 0) ws[t >> 6] = s;
    __syncthreads();
    if (t == 0) partial[blockIdx.x] = ws[0] + ws[1] + ws[2] + ws[3];
}

// scan phase 2: exclusive scan of the NSB partials (single small block)
__global__ __launch_bounds__(256) void k_scan2(int* __restrict__ partial) {
    __shared__ int s[256];
    int t = threadIdx.x;
    int v = (t < NSB) ? partial[t] : 0;
    s[t] = v;
    __syncthreads();
    for (int off = 1; off < 256; off <<= 1) {
        int u = (t >= off) ? s[t - off] : 0;
        __syncthreads();
        s[t] += u;
        __syncthreads();
    }
    if (t < NSB) partial[t] = s[t] - v;  // exclusive
}

// scan phase 3: within-chunk scan-then-propagate; write offsets + cursor
__global__ __launch_bounds__(256) void k_scan3(const int* __restrict__ degree,
                                               const int* __restrict__ partial,
                                               int* __restrict__ offsets,
                                               int* __restrict__ cursor) {
    __shared__ int s[256];
    int t = threadIdx.x;
    int i0 = blockIdx.x * SCHUNK + t * 2;
    int e0 = (i0 < NN) ? degree[i0] : 0;
    int e1 = (i0 + 1 < NN) ? degree[i0 + 1] : 0;
    int tsum = e0 + e1;
    s[t] = tsum;
    __syncthreads();
    for (int off = 1; off < 256; off <<= 1) {
        int u = (t >= off) ? s[t - off] : 0;
        __syncthreads();
        s[t] += u;
        __syncthreads();
    }
    int p0 = partial[blockIdx.x] + s[t] - tsum;  // exclusive prefix of e0
    if (i0 < NN)     { offsets[i0] = p0;          cursor[i0] = p0; }
    if (i0 + 1 < NN) { offsets[i0 + 1] = p0 + e0; cursor[i0 + 1] = p0 + e0; }
    if (i0 == NN - 1)     offsets[NN] = p0 + e0;
    if (i0 + 1 == NN - 1) offsets[NN] = p0 + e0 + e1;
}

__global__ void k_bucket(const int* src, const int* dst, const int* etype,
                         int* cursor, int* packed) {
    int e = blockIdx.x * blockDim.x + threadIdx.x;
    if (e < NE) {
        int d = dst[e];
        int pos = atomicAdd(&cursor[d], 1);
        packed[pos] = src[e] | (etype[e] << 20);
    }
}

// gather: mean of x[src] (64f) + relation-type fractions. One wave per node.
__global__ __launch_bounds__(256) void k_agg1(
    const int* __restrict__ offsets, const int* __restrict__ packed,
    const float* __restrict__ x, float* __restrict__ aggx, float* __restrict__ fc) {
    int node = (blockIdx.x * 256 + threadIdx.x) >> 6;
    int lane = threadIdx.x & 63;
    int beg = offsets[node], end = offsets[node + 1];
    float s0 = 0.f, s1 = 0.f, s2 = 0.f, s3 = 0.f;
    int c0 = 0, c1 = 0, c2 = 0;
    int e = beg;
    for (; e + 4 <= end; e += 4) {
        int p0 = packed[e], p1 = packed[e + 1], p2 = packed[e + 2], p3 = packed[e + 3];
        s0 += x[(p0 & 0xFFFFF) * EMB + lane];
        s1 += x[(p1 & 0xFFFFF) * EMB + lane];
        s2 += x[(p2 & 0xFFFFF) * EMB + lane];
        s3 += x[(p3 & 0xFFFFF) * EMB + lane];
        int t0 = p0 >> 20, t1 = p1 >> 20, t2 = p2 >> 20, t3 = p3 >> 20;
        c0 += (t0 == 0) + (t1 == 0) + (t2 == 0) + (t3 == 0);
        c1 += (t0 == 1) + (t1 == 1) + (t2 == 1) + (t3 == 1);
        c2 += (t0 == 2) + (t1 == 2) + (t2 == 2) + (t3 == 2);
    }
    for (; e < end; ++e) {
        int p = packed[e];
        s0 += x[(p & 0xFFFFF) * EMB + lane];
        int t = p >> 20;
        c0 += (t == 0); c1 += (t == 1); c2 += (t == 2);
    }
    float inv = 1.0f / (float)max(end - beg, 1);
    aggx[node * EMB + lane] = (s0 + s1 + s2 + s3) * inv;
    if (lane == 0)
        *(float4*)&fc[node * 4] = make_float4(c0 * inv, c1 * inv, c2 * inv, 0.f);
}

// gather: mean of h[src] (128f). One wave per node, 2 feats/lane, unroll 2 edges.
__global__ __launch_bounds__(256) void k_agg2(
    const int* __restrict__ offsets, const int* __restrict__ packed,
    const float* __restrict__ h, float* __restrict__ aggh) {
    int node = (blockIdx.x * 256 + threadIdx.x) >> 6;
    int lane = threadIdx.x & 63;
    int beg = offsets[node], end = offsets[node + 1];
    float a0 = 0.f, a1 = 0.f, b0 = 0.f, b1 = 0.f;
    int e = beg;
    for (; e + 2 <= end; e += 2) {
        int p0 = packed[e], p1 = packed[e + 1];
        const float* r0 = &h[(p0 & 0xFFFFF) * HID];
        const float* r1 = &h[(p1 & 0xFFFFF) * HID];
        a0 += r0[lane]; a1 += r0[lane + 64];
        b0 += r1[lane]; b1 += r1[lane + 64];
    }
    if (e < end) {
        const float* r0 = &h[(packed[e] & 0xFFFFF) * HID];
        a0 += r0[lane]; a1 += r0[lane + 64];
    }
    float inv = 1.0f / (float)max(end - beg, 1);
    aggh[node * HID + lane] = (a0 + b0) * inv;
    aggh[node * HID + 64 + lane] = (a1 + b1) * inv;
}

// register-tiled GEMM layer1: C[64m x 128n] per block, K=128 ([aggx|x] @ [w1x;w1r])
__global__ __launch_bounds__(256) void k_gemm1(
    const float* __restrict__ aggx, const float* __restrict__ x,
    const float* __restrict__ fc,
    const float* __restrict__ w1l, const float* __restrict__ w1r,
    const float* __restrict__ b1, const float* __restrict__ relp,
    float* __restrict__ h) {
    __shared__ float As[32][65];
    __shared__ float Bs[32][132];
    __shared__ float s_epi[512];
    int tid = threadIdx.x;
    int mbase = blockIdx.x * 64;
    for (int i = tid; i < 512; i += 256)
        s_epi[i] = (i < 128) ? b1[i] : relp[i - 128];
    float acc[4][8];
    #pragma unroll
    for (int i = 0; i < 4; ++i)
        #pragma unroll
        for (int j = 0; j < 8; ++j) acc[i][j] = 0.f;
    const int m0 = (tid >> 4) * 4;
    const int n0 = (tid & 15) * 4;
    const int aln = tid >> 2;
    const int akk = (tid & 3) * 8;
    const int anode = min(mbase + aln, NN - 1);
    const int br = tid >> 3;
    const int bc = (tid & 7) * 16;
    #pragma unroll
    for (int step = 0; step < 4; ++step) {
        const int k0 = step * 32;
        const float* ap = (k0 < 64) ? &aggx[anode * EMB + k0 + akk]
                                    : &x[anode * EMB + (k0 - 64) + akk];
        float4 av0 = *(const float4*)ap;
        float4 av1 = *(const float4*)(ap + 4);
        const int gr = k0 + br;
        const float* bp = (gr < 64) ? &w1l[gr * HID + bc] : &w1r[(gr - 64) * HID + bc];
        float4 bv0 = *(const float4*)bp;
        float4 bv1 = *(const float4*)(bp + 4);
        float4 bv2 = *(const float4*)(bp + 8);
        float4 bv3 = *(const float4*)(bp + 12);
        __syncthreads();
        As[akk + 0][aln] = av0.x; As[akk + 1][aln] = av0.y;
        As[akk + 2][aln] = av0.z; As[akk + 3][aln] = av0.w;
        As[akk + 4][aln] = av1.x; As[akk + 5][aln] = av1.y;
        As[akk + 6][aln] = av1.z; As[akk + 7][aln] = av1.w;
        *(float4*)&Bs[br][bc] = bv0;
        *(float4*)&Bs[br][bc + 4] = bv1;
        *(float4*)&Bs[br][bc + 8] = bv2;
        *(float4*)&Bs[br][bc + 12] = bv3;
        __syncthreads();
        #pragma unroll 8
        for (int kk = 0; kk < 32; ++kk) {
            float4 a = *(const float4*)&As[kk][m0];
            float4 bl = *(const float4*)&Bs[kk][n0];
            float4 bh = *(const float4*)&Bs[kk][n0 + 64];
            float am[4] = {a.x, a.y, a.z, a.w};
            float bb[8] = {bl.x, bl.y, bl.z, bl.w, bh.x, bh.y, bh.z, bh.w};
            #pragma unroll
            for (int mi = 0; mi < 4; ++mi)
                #pragma unroll
                for (int ni = 0; ni < 8; ++ni)
                    acc[mi][ni] += am[mi] * bb[ni];
        }
    }
    #pragma unroll
    for (int mi = 0; mi < 4; ++mi) {
        int node = mbase + m0 + mi;
        if (node >= NN) continue;
        float4 f = *(const float4*)&fc[node * 4];
        float o[8];
        #pragma unroll
        for (int ni = 0; ni < 8; ++ni) {
            int c = (ni < 4) ? (n0 + ni) : (n0 + 60 + ni);
            float v = acc[mi][ni] + s_epi[c]
                    + f.x * s_epi[128 + c] + f.y * s_epi[256 + c] + f.z * s_epi[384 + c];
            o[ni] = fmaxf(v, 0.f);
        }
        *(float4*)&h[node * HID + n0] = make_float4(o[0], o[1], o[2], o[3]);
        *(float4*)&h[node * HID + n0 + 64] = make_float4(o[4], o[5], o[6], o[7]);
    }
}

// register-tiled GEMM layer2: K=256 ([aggh|h] @ [w2l;w2r]), epilogue: +b2, pooled atomicMax
__global__ __launch_bounds__(256) void k_gemm2(
    const float* __restrict__ aggh, const float* __restrict__ h,
    const float* __restrict__ w2l, const float* __restrict__ w2r,
    const float* __restrict__ b2, const int* __restrict__ batch,
    unsigned* __restrict__ genc) {
    __shared__ float As[32][65];
    __shared__ float Bs[32][132];
    __shared__ float s_b2[128];
    int tid = threadIdx.x;
    int mbase = blockIdx.x * 64;
    if (tid < 128) s_b2[tid] = b2[tid];
    float acc[4][8];
    #pragma unroll
    for (int i = 0; i < 4; ++i)
        #pragma unroll
        for (int j = 0; j < 8; ++j) acc[i][j] = 0.f;
    const int m0 = (tid >> 4) * 4;
    const int n0 = (tid & 15) * 4;
    const int aln = tid >> 2;
    const int akk = (tid & 3) * 8;
    const int anode = min(mbase + aln, NN - 1);
    const int br = tid >> 3;
    const int bc = (tid & 7) * 16;
    #pragma unroll
    for (int step = 0; step < 8; ++step) {
        const int k0 = step * 32;
        const float* ap = (k0 < 128) ? &aggh[anode * HID + k0 + akk]
                                     : &h[anode * HID + (k0 - 128) + akk];
        float4 av0 = *(const float4*)ap;
        float4 av1 = *(const float4*)(ap + 4);
        const int gr = k0 + br;
        const float* bp = (gr < 128) ? &w2l[gr * HID + bc] : &w2r[(gr - 128) * HID + bc];
        float4 bv0 = *(const float4*)bp;
        float4 bv1 = *(const float4*)(bp + 4);
        float4 bv2 = *(const float4*)(bp + 8);
        float4 bv3 = *(const float4*)(bp + 12);
        __syncthreads();
        As[akk + 0][aln] = av0.x; As[akk + 1][aln] = av0.y;
        As[akk + 2][aln] = av0.z; As[akk + 3][aln] = av0.w;
        As[akk + 4][aln] = av1.x; As[akk + 5][aln] = av1.y;
        As[akk + 6][aln] = av1.z; As[akk + 7][aln] = av1.w;
        *(float4*)&Bs[br][bc] = bv0;
        *(float4*)&Bs[br][bc + 4] = bv1;
        *(float4*)&Bs[br][bc + 8] = bv2;
        *(float4*)&Bs[br][bc + 12] = bv3;
        __syncthreads();
        #pragma unroll 8
        for (int kk = 0; kk < 32; ++kk) {
            float4 a = *(const float4*)&As[kk][m0];
            float4 bl = *(const float4*)&Bs[kk][n0];
            float4 bh = *(const float4*)&Bs[kk][n0 + 64];
            float am[4] = {a.x, a.y, a.z, a.w};
            float bb[8] = {bl.x, bl.y, bl.z, bl.w, bh.x, bh.y, bh.z, bh.w};
            #pragma unroll
            for (int mi = 0; mi < 4; ++mi)
                #pragma unroll
                for (int ni = 0; ni < 8; ++ni)
                    acc[mi][ni] += am[mi] * bb[ni];
        }
    }
    int nd[4], bt[4];
    bool allok = true;
    #pragma unroll
    for (int mi = 0; mi < 4; ++mi) {
        nd[mi] = mbase + m0 + mi;
        bool ok = nd[mi] < NN;
        allok = allok && ok;
        bt[mi] = ok ? batch[nd[mi]] : -1;
    }
    bool same = allok && (bt[0] == bt[1]) && (bt[1] == bt[2]) && (bt[2] == bt[3]);
    if (same) {
        #pragma unroll
        for (int ni = 0; ni < 8; ++ni) {
            int c = (ni < 4) ? (n0 + ni) : (n0 + 60 + ni);
            float v = fmaxf(fmaxf(acc[0][ni], acc[1][ni]), fmaxf(acc[2][ni], acc[3][ni]));
            atomicMax(&genc[bt[0] * HID + c], fenc(v + s_b2[c]));
        }
    } else {
        #pragma unroll
        for (int mi = 0; mi < 4; ++mi) {
            if (nd[mi] >= NN) continue;
            #pragma unroll
            for (int ni = 0; ni < 8; ++ni) {
                int c = (ni < 4) ? (n0 + ni) : (n0 + 60 + ni);
                atomicMax(&genc[bt[mi] * HID + c], fenc(acc[mi][ni] + s_b2[c]));
            }
        }
    }
}

__global__ void k_final(const unsigned* __restrict__ genc,
                        const float* __restrict__ lin_w, const float* __restrict__ lin_b,
                        float* __restrict__ out) {
    int gr = blockIdx.x;
    int lane = threadIdx.x;  // 64
    float g0 = fmaxf(fdec(genc[gr * HID + lane]), 0.f);
    float g1 = fmaxf(fdec(genc[gr * HID + 64 + lane]), 0.f);
    #pragma unroll
    for (int c = 0; c < NCLS; ++c) {
        float p = g0 * lin_w[lane * NCLS + c] + g1 * lin_w[(lane + 64) * NCLS + c];
        for (int off = 32; off > 0; off >>= 1)
            p += __shfl_down(p, off, 64);
        if (lane == 0) out[gr * NCLS + c] = p + lin_b[c];
    }
}

extern "C" void kernel_launch(void* const* d_in, const int* in_sizes, int n_in,
                              void* d_out, int out_size, void* d_ws, size_t ws_size,
                              hipStream_t stream) {
    const int* x_tokens   = (const int*)d_in[0];
    const int* edge_index = (const int*)d_in[1];
    const int* edge_type  = (const int*)d_in[2];
    const int* batch      = (const int*)d_in[3];
    const float* emb_table = (const float*)d_in[5];
    const float* rel_table = (const float*)d_in[6];
    const float* w1_l = (const float*)d_in[7];
    const float* b1   = (const float*)d_in[8];
    const float* w1_r = (const float*)d_in[9];
    const float* w2_l = (const float*)d_in[10];
    const float* b2   = (const float*)d_in[11];
    const float* w2_r = (const float*)d_in[12];
    const float* lin_w = (const float*)d_in[13];
    const float* lin_b = (const float*)d_in[14];
    float* out = (float*)d_out;

    const int* src = edge_index;
    const int* dst = edge_index + NE;

    char* ws = (char*)d_ws;
    size_t off = 0;
    auto alloc = [&](size_t bytes) {
        void* p = ws + off;
        off = (off + bytes + 255) & ~(size_t)255;
        return p;
    };
    float* region0 = (float*)alloc((size_t)NN * HID * 4);   // x|aggx, later aggh
    float* x    = region0;
    float* aggx = region0 + (size_t)NN * EMB;
    float* aggh = region0;
    float* h    = (float*)alloc((size_t)NN * HID * 4);
    float* fc   = (float*)alloc((size_t)NN * 4 * 4);
    int* degree  = (int*)alloc((size_t)NN * 4);
    int* offsets = (int*)alloc((size_t)(NN + 1) * 4);
    int* cursor  = (int*)alloc((size_t)NN * 4);
    int* packed  = (int*)alloc((size_t)NE * 4);
    unsigned* genc = (unsigned*)alloc((size_t)NG * HID * 4);
    float* relp  = (float*)alloc((size_t)3 * HID * 4);
    int* partial = (int*)alloc((size_t)256 * 4);
    (void)ws_size; (void)in_sizes; (void)n_in; (void)out_size;

    const int MT = (NN + 63) / 64;

    hipLaunchKernelGGL(k_init,   dim3((NG * HID + 255) / 256), dim3(256), 0, stream,
                       degree, genc, relp, rel_table, w1_l);
    hipLaunchKernelGGL(k_embed,  dim3(NN * EMB / 256), dim3(256), 0, stream,
                       x_tokens, emb_table, x);
    hipLaunchKernelGGL(k_degree, dim3((NE + 255) / 256), dim3(256), 0, stream, dst, degree);
    hipLaunchKernelGGL(k_scan1,  dim3(NSB), dim3(256), 0, stream, degree, partial);
    hipLaunchKernelGGL(k_scan2,  dim3(1), dim3(256), 0, stream, partial);
    hipLaunchKernelGGL(k_scan3,  dim3(NSB), dim3(256), 0, stream,
                       degree, partial, offsets, cursor);
    hipLaunchKernelGGL(k_bucket, dim3((NE + 255) / 256), dim3(256), 0, stream,
                       src, dst, edge_type, cursor, packed);
    hipLaunchKernelGGL(k_agg1,   dim3(NN / 4), dim3(256), 0, stream,
                       offsets, packed, x, aggx, fc);
    hipLaunchKernelGGL(k_gemm1,  dim3(MT), dim3(256), 0, stream,
                       aggx, x, fc, w1_l, w1_r, b1, relp, h);
    hipLaunchKernelGGL(k_agg2,   dim3(NN / 4), dim3(256), 0, stream,
                       offsets, packed, h, aggh);
    hipLaunchKernelGGL(k_gemm2,  dim3(MT), dim3(256), 0, stream,
                       aggh, h, w2_l, w2_r, b2, batch, genc);
    hipLaunchKernelGGL(k_final,  dim3(NG), dim3(64), 0, stream, genc, lin_w, lin_b, out);
}

// Round 4
// 295.064 us; speedup vs baseline: 4.5817x; 1.3507x over previous
//
#include <hip/hip_runtime.h>
#include <hip/hip_bf16.h>

#define NN 100000
#define NE 800000
#define NG 2000
#define EMB 64
#define HID 128
#define NCLS 10
#define SCHUNK 512
#define NSB ((NN + SCHUNK - 1) / SCHUNK)   // 196 scan blocks

typedef __attribute__((ext_vector_type(8))) short short8;
typedef __attribute__((ext_vector_type(4))) float f32x4;
typedef unsigned short u16;
typedef unsigned int u32;

// monotone float<->uint encoding so unsigned atomicMax == float max
static __device__ __forceinline__ unsigned fenc(float f) {
    unsigned u = __float_as_uint(f);
    return (u & 0x80000000u) ? ~u : (u | 0x80000000u);
}
static __device__ __forceinline__ float fdec(unsigned u) {
    return (u & 0x80000000u) ? __uint_as_float(u & 0x7FFFFFFFu) : __uint_as_float(~u);
}
// fp32 -> bf16 (RNE)
static __device__ __forceinline__ u16 f2bf(float f) {
    u32 u = __float_as_uint(f);
    return (u16)((u + 0x7FFFu + ((u >> 16) & 1u)) >> 16);
}
static __device__ __forceinline__ float bfu(u16 v) {
    return __uint_as_float(((u32)v) << 16);
}

__global__ void k_init(int* degree, unsigned* genc, float* relp,
                       u16* Bt1, u16* Bt2,
                       const float* rel_table, const float* w1l, const float* w1r,
                       const float* w2l, const float* w2r) {
    int i = blockIdx.x * 256 + threadIdx.x;   // grid covers 256000
    if (i < NN) degree[i] = 0;
    if (i < NG * HID) genc[i] = 0x007FFFFFu;  // fenc(-inf)
    if (i < 3 * HID) {
        int t = i >> 7, j = i & 127;
        float s = 0.f;
        for (int k = 0; k < 16; ++k)
            s += rel_table[t * 16 + k] * w1l[(64 + k) * HID + j];
        relp[i] = s;
    }
    if (i < 128 * 128) {   // Bt1[c][k] = B1[k][c], B1 = [w1l[0:64]; w1r]
        int c = i >> 7, k = i & 127;
        float w = (k < 64) ? w1l[k * HID + c] : w1r[(k - 64) * HID + c];
        Bt1[c * 128 + k] = f2bf(w);
    }
    if (i < 128 * 256) {   // Bt2[c][k] = B2[k][c], B2 = [w2l; w2r]
        int c = i >> 8, k = i & 255;
        float w = (k < 128) ? w2l[k * HID + c] : w2r[(k - 128) * HID + c];
        Bt2[c * 256 + k] = f2bf(w);
    }
}

// embedding gather -> bf16 x [NN][64]; thread handles 2 features
__global__ void k_embed(const int* __restrict__ tok, const float* __restrict__ emb,
                        u32* __restrict__ xb) {
    int i = blockIdx.x * 256 + threadIdx.x;   // < NN*32
    int n = i >> 5, p = i & 31;
    float2 e = *(const float2*)&emb[tok[n] * EMB + p * 2];
    xb[i] = (u32)f2bf(e.x) | ((u32)f2bf(e.y) << 16);
}

__global__ void k_degree(const int* dst, int* degree) {
    int e = blockIdx.x * blockDim.x + threadIdx.x;
    if (e < NE) atomicAdd(&degree[dst[e]], 1);
}

__global__ __launch_bounds__(256) void k_scan1(const int* __restrict__ degree,
                                               int* __restrict__ partial) {
    __shared__ int ws[4];
    int t = threadIdx.x;
    int i0 = blockIdx.x * SCHUNK + t * 2;
    int e0 = (i0 < NN) ? degree[i0] : 0;
    int e1 = (i0 + 1 < NN) ? degree[i0 + 1] : 0;
    int s = e0 + e1;
    for (int off = 32; off > 0; off >>= 1) s += __shfl_down(s, off, 64);
    if ((t & 63) == 0) ws[t >> 6] = s;
    __syncthreads();
    if (t == 0) partial[blockIdx.x] = ws[0] + ws[1] + ws[2] + ws[3];
}

__global__ __launch_bounds__(256) void k_scan2(int* __restrict__ partial) {
    __shared__ int s[256];
    int t = threadIdx.x;
    int v = (t < NSB) ? partial[t] : 0;
    s[t] = v;
    __syncthreads();
    for (int off = 1; off < 256; off <<= 1) {
        int u = (t >= off) ? s[t - off] : 0;
        __syncthreads();
        s[t] += u;
        __syncthreads();
    }
    if (t < NSB) partial[t] = s[t] - v;  // exclusive
}

__global__ __launch_bounds__(256) void k_scan3(const int* __restrict__ degree,
                                               const int* __restrict__ partial,
                                               int* __restrict__ offsets,
                                               int* __restrict__ cursor) {
    __shared__ int s[256];
    int t = threadIdx.x;
    int i0 = blockIdx.x * SCHUNK + t * 2;
    int e0 = (i0 < NN) ? degree[i0] : 0;
    int e1 = (i0 + 1 < NN) ? degree[i0 + 1] : 0;
    int tsum = e0 + e1;
    s[t] = tsum;
    __syncthreads();
    for (int off = 1; off < 256; off <<= 1) {
        int u = (t >= off) ? s[t - off] : 0;
        __syncthreads();
        s[t] += u;
        __syncthreads();
    }
    int p0 = partial[blockIdx.x] + s[t] - tsum;
    if (i0 < NN)     { offsets[i0] = p0;          cursor[i0] = p0; }
    if (i0 + 1 < NN) { offsets[i0 + 1] = p0 + e0; cursor[i0 + 1] = p0 + e0; }
    if (i0 == NN - 1)     offsets[NN] = p0 + e0;
    if (i0 + 1 == NN - 1) offsets[NN] = p0 + e0 + e1;
}

__global__ void k_bucket(const int* src, const int* dst, const int* etype,
                         int* cursor, int* packed) {
    int e = blockIdx.x * blockDim.x + threadIdx.x;
    if (e < NE) {
        int d = dst[e];
        int pos = atomicAdd(&cursor[d], 1);
        packed[pos] = src[e] | (etype[e] << 20);
    }
}

// gather: mean of x[src] (64 bf16) + relation-type fractions. One wave per node.
__global__ __launch_bounds__(256) void k_agg1(
    const int* __restrict__ offsets, const int* __restrict__ packed,
    const u16* __restrict__ xb, u16* __restrict__ aggx, float* __restrict__ fc) {
    int node = (blockIdx.x * 256 + threadIdx.x) >> 6;
    int lane = threadIdx.x & 63;
    int beg = offsets[node], end = offsets[node + 1];
    float s0 = 0.f, s1 = 0.f, s2 = 0.f, s3 = 0.f;
    int c0 = 0, c1 = 0, c2 = 0;
    int e = beg;
    for (; e + 4 <= end; e += 4) {
        int p0 = packed[e], p1 = packed[e + 1], p2 = packed[e + 2], p3 = packed[e + 3];
        s0 += bfu(xb[(p0 & 0xFFFFF) * EMB + lane]);
        s1 += bfu(xb[(p1 & 0xFFFFF) * EMB + lane]);
        s2 += bfu(xb[(p2 & 0xFFFFF) * EMB + lane]);
        s3 += bfu(xb[(p3 & 0xFFFFF) * EMB + lane]);
        int t0 = p0 >> 20, t1 = p1 >> 20, t2 = p2 >> 20, t3 = p3 >> 20;
        c0 += (t0 == 0) + (t1 == 0) + (t2 == 0) + (t3 == 0);
        c1 += (t0 == 1) + (t1 == 1) + (t2 == 1) + (t3 == 1);
        c2 += (t0 == 2) + (t1 == 2) + (t2 == 2) + (t3 == 2);
    }
    for (; e < end; ++e) {
        int p = packed[e];
        s0 += bfu(xb[(p & 0xFFFFF) * EMB + lane]);
        int t = p >> 20;
        c0 += (t == 0); c1 += (t == 1); c2 += (t == 2);
    }
    float inv = 1.0f / (float)max(end - beg, 1);
    aggx[node * EMB + lane] = f2bf((s0 + s1 + s2 + s3) * inv);
    if (lane == 0)
        *(float4*)&fc[node * 4] = make_float4(c0 * inv, c1 * inv, c2 * inv, 0.f);
}

// gather: mean of h[src] (128 bf16 = 64 dwords). One wave per node, unroll 2 edges.
__global__ __launch_bounds__(256) void k_agg2(
    const int* __restrict__ offsets, const int* __restrict__ packed,
    const u32* __restrict__ hb, u32* __restrict__ aggh) {
    int node = (blockIdx.x * 256 + threadIdx.x) >> 6;
    int lane = threadIdx.x & 63;
    int beg = offsets[node], end = offsets[node + 1];
    float a0 = 0.f, a1 = 0.f, b0 = 0.f, b1 = 0.f;
    int e = beg;
    for (; e + 2 <= end; e += 2) {
        u32 u = hb[(packed[e] & 0xFFFFF) * 64 + lane];
        u32 v = hb[(packed[e + 1] & 0xFFFFF) * 64 + lane];
        a0 += __uint_as_float(u << 16);
        a1 += __uint_as_float(u & 0xFFFF0000u);
        b0 += __uint_as_float(v << 16);
        b1 += __uint_as_float(v & 0xFFFF0000u);
    }
    if (e < end) {
        u32 u = hb[(packed[e] & 0xFFFFF) * 64 + lane];
        a0 += __uint_as_float(u << 16);
        a1 += __uint_as_float(u & 0xFFFF0000u);
    }
    float inv = 1.0f / (float)max(end - beg, 1);
    aggh[node * 64 + lane] = (u32)f2bf((a0 + b0) * inv) | ((u32)f2bf((a1 + b1) * inv) << 16);
}

// MFMA GEMM layer1: C[64 x 128] per block, K=128 ([aggx|x] @ Bt1^T)
// per wave: M=32 (2 frags) x N=64 (4 frags). Epilogue: +b1 +fc.relp, relu -> bf16 h
__global__ __launch_bounds__(256) void k_gemm1(
    const u16* __restrict__ aggx, const u16* __restrict__ xb,
    const float* __restrict__ fc, const u16* __restrict__ Bt1,
    const float* __restrict__ b1, const float* __restrict__ relp,
    u16* __restrict__ h) {
    int tid = threadIdx.x;
    int lane = tid & 63, wid = tid >> 6;
    int wm = wid >> 1, wn = wid & 1;
    int mbase = blockIdx.x * 64;
    int ra = min(mbase + wm * 32 + (lane & 15), NN - 1);
    int rb = min(mbase + wm * 32 + 16 + (lane & 15), NN - 1);
    int kg = (lane >> 4) * 8;
    f32x4 acc[2][4] = {};
    #pragma unroll
    for (int step = 0; step < 4; ++step) {
        int kk = step * 32 + kg;
        const u16* pa;
        const u16* pb;
        if (step < 2) { pa = aggx + ra * EMB + kk;       pb = aggx + rb * EMB + kk; }
        else          { pa = xb   + ra * EMB + kk - 64;  pb = xb   + rb * EMB + kk - 64; }
        short8 a0 = *(const short8*)pa;
        short8 a1 = *(const short8*)pb;
        #pragma unroll
        for (int nf = 0; nf < 4; ++nf) {
            short8 b = *(const short8*)(Bt1 + (wn * 64 + nf * 16 + (lane & 15)) * 128 + kk);
            acc[0][nf] = __builtin_amdgcn_mfma_f32_16x16x32_bf16(a0, b, acc[0][nf], 0, 0, 0);
            acc[1][nf] = __builtin_amdgcn_mfma_f32_16x16x32_bf16(a1, b, acc[1][nf], 0, 0, 0);
        }
    }
    // epilogue constants per nf-column
    float eb[4], e0[4], e1[4], e2[4];
    #pragma unroll
    for (int nf = 0; nf < 4; ++nf) {
        int c = wn * 64 + nf * 16 + (lane & 15);
        eb[nf] = b1[c]; e0[nf] = relp[c]; e1[nf] = relp[128 + c]; e2[nf] = relp[256 + c];
    }
    #pragma unroll
    for (int mi = 0; mi < 2; ++mi) {
        #pragma unroll
        for (int reg = 0; reg < 4; ++reg) {
            int row = mbase + wm * 32 + mi * 16 + (lane >> 4) * 4 + reg;
            if (row >= NN) continue;
            float4 f = *(const float4*)&fc[row * 4];
            #pragma unroll
            for (int nf = 0; nf < 4; ++nf) {
                int c = wn * 64 + nf * 16 + (lane & 15);
                float v = acc[mi][nf][reg] + eb[nf] + f.x * e0[nf] + f.y * e1[nf] + f.z * e2[nf];
                h[row * HID + c] = f2bf(fmaxf(v, 0.f));
            }
        }
    }
}

// MFMA GEMM layer2: K=256 ([aggh|h] @ Bt2^T), epilogue: +b2, pooled atomicMax
__global__ __launch_bounds__(256) void k_gemm2(
    const u16* __restrict__ aggh, const u16* __restrict__ h,
    const u16* __restrict__ Bt2, const float* __restrict__ b2,
    const int* __restrict__ batch, unsigned* __restrict__ genc) {
    int tid = threadIdx.x;
    int lane = tid & 63, wid = tid >> 6;
    int wm = wid >> 1, wn = wid & 1;
    int mbase = blockIdx.x * 64;
    int ra = min(mbase + wm * 32 + (lane & 15), NN - 1);
    int rb = min(mbase + wm * 32 + 16 + (lane & 15), NN - 1);
    int kg = (lane >> 4) * 8;
    f32x4 acc[2][4] = {};
    #pragma unroll
    for (int step = 0; step < 8; ++step) {
        int kk = step * 32 + kg;
        const u16* pa;
        const u16* pb;
        if (step < 4) { pa = aggh + ra * HID + kk;        pb = aggh + rb * HID + kk; }
        else          { pa = h    + ra * HID + kk - 128;  pb = h    + rb * HID + kk - 128; }
        short8 a0 = *(const short8*)pa;
        short8 a1 = *(const short8*)pb;
        #pragma unroll
        for (int nf = 0; nf < 4; ++nf) {
            short8 b = *(const short8*)(Bt2 + (wn * 64 + nf * 16 + (lane & 15)) * 256 + kk);
            acc[0][nf] = __builtin_amdgcn_mfma_f32_16x16x32_bf16(a0, b, acc[0][nf], 0, 0, 0);
            acc[1][nf] = __builtin_amdgcn_mfma_f32_16x16x32_bf16(a1, b, acc[1][nf], 0, 0, 0);
        }
    }
    float bv[4];
    #pragma unroll
    for (int nf = 0; nf < 4; ++nf) bv[nf] = b2[wn * 64 + nf * 16 + (lane & 15)];
    #pragma unroll
    for (int mi = 0; mi < 2; ++mi) {
        int r0 = mbase + wm * 32 + mi * 16 + (lane >> 4) * 4;
        if (r0 >= NN) continue;
        if (r0 + 3 < NN && batch[r0] == batch[r0 + 3]) {
            int bt = batch[r0];
            #pragma unroll
            for (int nf = 0; nf < 4; ++nf) {
                int c = wn * 64 + nf * 16 + (lane & 15);
                f32x4 a = acc[mi][nf];
                float v = fmaxf(fmaxf(a[0], a[1]), fmaxf(a[2], a[3])) + bv[nf];
                atomicMax(&genc[bt * HID + c], fenc(v));
            }
        } else {
            #pragma unroll
            for (int reg = 0; reg < 4; ++reg) {
                int row = r0 + reg;
                if (row >= NN) continue;
                int bt = batch[row];
                #pragma unroll
                for (int nf = 0; nf < 4; ++nf) {
                    int c = wn * 64 + nf * 16 + (lane & 15);
                    atomicMax(&genc[bt * HID + c], fenc(acc[mi][nf][reg] + bv[nf]));
                }
            }
        }
    }
}

__global__ void k_final(const unsigned* __restrict__ genc,
                        const float* __restrict__ lin_w, const float* __restrict__ lin_b,
                        float* __restrict__ out) {
    int gr = blockIdx.x;
    int lane = threadIdx.x;  // 64
    float g0 = fmaxf(fdec(genc[gr * HID + lane]), 0.f);
    float g1 = fmaxf(fdec(genc[gr * HID + 64 + lane]), 0.f);
    #pragma unroll
    for (int c = 0; c < NCLS; ++c) {
        float p = g0 * lin_w[lane * NCLS + c] + g1 * lin_w[(lane + 64) * NCLS + c];
        for (int off = 32; off > 0; off >>= 1)
            p += __shfl_down(p, off, 64);
        if (lane == 0) out[gr * NCLS + c] = p + lin_b[c];
    }
}

extern "C" void kernel_launch(void* const* d_in, const int* in_sizes, int n_in,
                              void* d_out, int out_size, void* d_ws, size_t ws_size,
                              hipStream_t stream) {
    const int* x_tokens   = (const int*)d_in[0];
    const int* edge_index = (const int*)d_in[1];
    const int* edge_type  = (const int*)d_in[2];
    const int* batch      = (const int*)d_in[3];
    const float* emb_table = (const float*)d_in[5];
    const float* rel_table = (const float*)d_in[6];
    const float* w1_l = (const float*)d_in[7];
    const float* b1   = (const float*)d_in[8];
    const float* w1_r = (const float*)d_in[9];
    const float* w2_l = (const float*)d_in[10];
    const float* b2   = (const float*)d_in[11];
    const float* w2_r = (const float*)d_in[12];
    const float* lin_w = (const float*)d_in[13];
    const float* lin_b = (const float*)d_in[14];
    float* out = (float*)d_out;

    const int* src = edge_index;
    const int* dst = edge_index + NE;

    char* ws = (char*)d_ws;
    size_t off = 0;
    auto alloc = [&](size_t bytes) {
        void* p = ws + off;
        off = (off + bytes + 255) & ~(size_t)255;
        return p;
    };
    u16* xb      = (u16*)alloc((size_t)NN * EMB * 2);    // 12.8 MB bf16
    u16* aggx    = (u16*)alloc((size_t)NN * EMB * 2);    // 12.8 MB
    u16* h       = (u16*)alloc((size_t)NN * HID * 2);    // 25.6 MB
    u16* aggh    = (u16*)alloc((size_t)NN * HID * 2);    // 25.6 MB
    float* fc    = (float*)alloc((size_t)NN * 4 * 4);
    int* degree  = (int*)alloc((size_t)NN * 4);
    int* offsets = (int*)alloc((size_t)(NN + 1) * 4);
    int* cursor  = (int*)alloc((size_t)NN * 4);
    int* packed  = (int*)alloc((size_t)NE * 4);
    unsigned* genc = (unsigned*)alloc((size_t)NG * HID * 4);
    float* relp  = (float*)alloc((size_t)3 * HID * 4);
    int* partial = (int*)alloc((size_t)256 * 4);
    u16* Bt1     = (u16*)alloc((size_t)128 * 128 * 2);
    u16* Bt2     = (u16*)alloc((size_t)128 * 256 * 2);
    (void)ws_size; (void)in_sizes; (void)n_in; (void)out_size;

    const int MT = (NN + 63) / 64;  // 1563

    hipLaunchKernelGGL(k_init,   dim3(1000), dim3(256), 0, stream,
                       degree, genc, relp, Bt1, Bt2, rel_table, w1_l, w1_r, w2_l, w2_r);
    hipLaunchKernelGGL(k_embed,  dim3(NN * 32 / 256), dim3(256), 0, stream,
                       x_tokens, emb_table, (u32*)xb);
    hipLaunchKernelGGL(k_degree, dim3((NE + 255) / 256), dim3(256), 0, stream, dst, degree);
    hipLaunchKernelGGL(k_scan1,  dim3(NSB), dim3(256), 0, stream, degree, partial);
    hipLaunchKernelGGL(k_scan2,  dim3(1), dim3(256), 0, stream, partial);
    hipLaunchKernelGGL(k_scan3,  dim3(NSB), dim3(256), 0, stream,
                       degree, partial, offsets, cursor);
    hipLaunchKernelGGL(k_bucket, dim3((NE + 255) / 256), dim3(256), 0, stream,
                       src, dst, edge_type, cursor, packed);
    hipLaunchKernelGGL(k_agg1,   dim3(NN / 4), dim3(256), 0, stream,
                       offsets, packed, xb, aggx, fc);
    hipLaunchKernelGGL(k_gemm1,  dim3(MT), dim3(256), 0, stream,
                       aggx, xb, fc, Bt1, b1, relp, h);
    hipLaunchKernelGGL(k_agg2,   dim3(NN / 4), dim3(256), 0, stream,
                       offsets, packed, (const u32*)h, (u32*)aggh);
    hipLaunchKernelGGL(k_gemm2,  dim3(MT), dim3(256), 0, stream,
                       aggh, h, Bt2, b2, batch, genc);
    hipLaunchKernelGGL(k_final,  dim3(NG), dim3(64), 0, stream, genc, lin_w, lin_b, out);
}

// Round 5
// 219.369 us; speedup vs baseline: 6.1627x; 1.3451x over previous
//
#include <hip/hip_runtime.h>
#include <hip/hip_bf16.h>

#define NN 100000
#define NE 800000
#define NG 2000
#define EMB 64
#define HID 128
#define NCLS 10

#define NBKT 196                       // coarse dst buckets (512 nodes each)
#define EPB 4096                       // edges per counting block
#define NBA ((NE + EPB - 1) / EPB)     // 196 counting blocks
#define NSCAN (NBKT * NBA)             // 38416
#define GS_NB ((NSCAN + 511) / 512)    // 76

typedef __attribute__((ext_vector_type(8))) short short8;
typedef __attribute__((ext_vector_type(4))) float f32x4;
typedef unsigned short u16;
typedef unsigned int u32;

// monotone float<->uint encoding so unsigned atomicMax == float max
static __device__ __forceinline__ unsigned fenc(float f) {
    unsigned u = __float_as_uint(f);
    return (u & 0x80000000u) ? ~u : (u | 0x80000000u);
}
static __device__ __forceinline__ float fdec(unsigned u) {
    return (u & 0x80000000u) ? __uint_as_float(u & 0x7FFFFFFFu) : __uint_as_float(~u);
}
static __device__ __forceinline__ u16 f2bf(float f) {
    u32 u = __float_as_uint(f);
    return (u16)((u + 0x7FFFu + ((u >> 16) & 1u)) >> 16);
}
static __device__ __forceinline__ float bfu(u16 v) {
    return __uint_as_float(((u32)v) << 16);
}

__global__ void k_init(unsigned* genc, float* relp, u16* Bt1, u16* Bt2,
                       const float* rel_table, const float* w1l, const float* w1r,
                       const float* w2l, const float* w2r) {
    int i = blockIdx.x * 256 + threadIdx.x;   // grid covers 256000
    if (i < NG * HID) genc[i] = 0x007FFFFFu;  // fenc(-inf)
    if (i < 3 * HID) {
        int t = i >> 7, j = i & 127;
        float s = 0.f;
        for (int k = 0; k < 16; ++k)
            s += rel_table[t * 16 + k] * w1l[(64 + k) * HID + j];
        relp[i] = s;
    }
    if (i < 128 * 128) {   // Bt1[c][k] = B1[k][c], B1 = [w1l[0:64]; w1r]
        int c = i >> 7, k = i & 127;
        float w = (k < 64) ? w1l[k * HID + c] : w1r[(k - 64) * HID + c];
        Bt1[c * 128 + k] = f2bf(w);
    }
    if (i < 128 * 256) {   // Bt2[c][k] = B2[k][c], B2 = [w2l; w2r]
        int c = i >> 8, k = i & 255;
        float w = (k < 128) ? w2l[k * HID + c] : w2r[(k - 128) * HID + c];
        Bt2[c * 256 + k] = f2bf(w);
    }
}

// embedding gather -> bf16 x [NN][64]; thread handles 2 features
__global__ void k_embed(const int* __restrict__ tok, const float* __restrict__ emb,
                        u32* __restrict__ xb) {
    int i = blockIdx.x * 256 + threadIdx.x;   // < NN*32
    int n = i >> 5, p = i & 31;
    float2 e = *(const float2*)&emb[tok[n] * EMB + p * 2];
    xb[i] = (u32)f2bf(e.x) | ((u32)f2bf(e.y) << 16);
}

// ---- atomic-free CSR build: two-level counting sort by dst ----

// pass A: per-(block, coarse-bucket) edge counts via LDS histogram
__global__ __launch_bounds__(256) void k_cnt(const int* __restrict__ dst,
                                             int* __restrict__ counts) {
    __shared__ int hist[NBKT];
    int t = threadIdx.x;
    for (int i = t; i < NBKT; i += 256) hist[i] = 0;
    __syncthreads();
    int base = blockIdx.x * EPB;
    for (int j = t; j < EPB; j += 256) {
        int e = base + j;
        if (e < NE) atomicAdd(&hist[dst[e] >> 9], 1);
    }
    __syncthreads();
    for (int i = t; i < NBKT; i += 256)
        counts[i * NBA + blockIdx.x] = hist[i];  // bucket-major for scan
}

// generic hierarchical scan over NSCAN ints
__global__ __launch_bounds__(256) void k_gs1(const int* __restrict__ v, int* __restrict__ part) {
    __shared__ int ws[4];
    int t = threadIdx.x;
    int i0 = blockIdx.x * 512 + t * 2;
    int e0 = (i0 < NSCAN) ? v[i0] : 0;
    int e1 = (i0 + 1 < NSCAN) ? v[i0 + 1] : 0;
    int s = e0 + e1;
    for (int off = 32; off > 0; off >>= 1) s += __shfl_down(s, off, 64);
    if ((t & 63) == 0) ws[t >> 6] = s;
    __syncthreads();
    if (t == 0) part[blockIdx.x] = ws[0] + ws[1] + ws[2] + ws[3];
}

__global__ __launch_bounds__(128) void k_gs2(int* __restrict__ part) {
    __shared__ int s[128];
    int t = threadIdx.x;
    int v = (t < GS_NB) ? part[t] : 0;
    s[t] = v;
    __syncthreads();
    for (int off = 1; off < 128; off <<= 1) {
        int u = (t >= off) ? s[t - off] : 0;
        __syncthreads();
        s[t] += u;
        __syncthreads();
    }
    if (t < GS_NB) part[t] = s[t] - v;  // exclusive
}

__global__ __launch_bounds__(256) void k_gs3(const int* __restrict__ v,
                                             const int* __restrict__ part,
                                             int* __restrict__ out) {
    __shared__ int s[256];
    int t = threadIdx.x;
    int i0 = blockIdx.x * 512 + t * 2;
    int e0 = (i0 < NSCAN) ? v[i0] : 0;
    int e1 = (i0 + 1 < NSCAN) ? v[i0 + 1] : 0;
    int tsum = e0 + e1;
    s[t] = tsum;
    __syncthreads();
    for (int off = 1; off < 256; off <<= 1) {
        int u = (t >= off) ? s[t - off] : 0;
        __syncthreads();
        s[t] += u;
        __syncthreads();
    }
    int p0 = part[blockIdx.x] + s[t] - tsum;
    if (i0 < NSCAN) out[i0] = p0;
    if (i0 + 1 < NSCAN) out[i0 + 1] = p0 + e0;
}

// pass B: scatter edges to coarse-bucket order (LDS cursors only)
// pack: src(17) | etype(2)<<17 | dstlow(9)<<19
__global__ __launch_bounds__(256) void k_part(const int* __restrict__ src,
                                              const int* __restrict__ dst,
                                              const int* __restrict__ et,
                                              const int* __restrict__ scanned,
                                              u32* __restrict__ coarse) {
    __shared__ int cur[NBKT];
    int t = threadIdx.x;
    for (int i = t; i < NBKT; i += 256) cur[i] = scanned[i * NBA + blockIdx.x];
    __syncthreads();
    int base = blockIdx.x * EPB;
    for (int j = t; j < EPB; j += 256) {
        int e = base + j;
        if (e < NE) {
            int d = dst[e];
            int pos = atomicAdd(&cur[d >> 9], 1);
            coarse[pos] = (u32)src[e] | ((u32)et[e] << 17) | ((u32)(d & 511) << 19);
        }
    }
}

// pass C: one block per coarse bucket -> fine CSR (offsets + packed)
__global__ __launch_bounds__(256) void k_csr(const int* __restrict__ scanned,
                                             const u32* __restrict__ coarse,
                                             int* __restrict__ offsets,
                                             int* __restrict__ packed) {
    __shared__ int hist[512];
    __shared__ int ex[512];
    __shared__ int ts[256];
    int b = blockIdx.x, t = threadIdx.x;
    int beg = scanned[b * NBA];
    int end = (b + 1 < NBKT) ? scanned[(b + 1) * NBA] : NE;
    hist[t] = 0; hist[t + 256] = 0;
    __syncthreads();
    for (int i = beg + t; i < end; i += 256)
        atomicAdd(&hist[(coarse[i] >> 19) & 511], 1);
    __syncthreads();
    int a0 = hist[2 * t], a1 = hist[2 * t + 1];
    int sum = a0 + a1;
    ts[t] = sum;
    __syncthreads();
    for (int off = 1; off < 256; off <<= 1) {
        int u = (t >= off) ? ts[t - off] : 0;
        __syncthreads();
        ts[t] += u;
        __syncthreads();
    }
    int ep = ts[t] - sum;
    ex[2 * t] = ep;
    ex[2 * t + 1] = ep + a0;
    __syncthreads();
    int node0 = b * 512;
    if (node0 + 2 * t < NN)     offsets[node0 + 2 * t]     = beg + ex[2 * t];
    if (node0 + 2 * t + 1 < NN) offsets[node0 + 2 * t + 1] = beg + ex[2 * t + 1];
    if (b == NBKT - 1 && t == 0) offsets[NN] = NE;
    // reuse hist as cursors
    hist[2 * t] = beg + ex[2 * t];
    hist[2 * t + 1] = beg + ex[2 * t + 1];
    __syncthreads();
    for (int i = beg + t; i < end; i += 256) {
        u32 pk = coarse[i];
        int pos = atomicAdd(&hist[(pk >> 19) & 511], 1);
        packed[pos] = (int)(pk & 0x1FFFFu) | (int)(((pk >> 17) & 3u) << 20);
    }
}

// gather: mean of x[src] (64 bf16) + relation-type fractions. One wave per node.
__global__ __launch_bounds__(256) void k_agg1(
    const int* __restrict__ offsets, const int* __restrict__ packed,
    const u16* __restrict__ xb, u16* __restrict__ aggx, float* __restrict__ fc) {
    int node = (blockIdx.x * 256 + threadIdx.x) >> 6;
    int lane = threadIdx.x & 63;
    int beg = offsets[node], end = offsets[node + 1];
    float s0 = 0.f, s1 = 0.f, s2 = 0.f, s3 = 0.f;
    int c0 = 0, c1 = 0, c2 = 0;
    int e = beg;
    for (; e + 4 <= end; e += 4) {
        int p0 = packed[e], p1 = packed[e + 1], p2 = packed[e + 2], p3 = packed[e + 3];
        s0 += bfu(xb[(p0 & 0xFFFFF) * EMB + lane]);
        s1 += bfu(xb[(p1 & 0xFFFFF) * EMB + lane]);
        s2 += bfu(xb[(p2 & 0xFFFFF) * EMB + lane]);
        s3 += bfu(xb[(p3 & 0xFFFFF) * EMB + lane]);
        int t0 = p0 >> 20, t1 = p1 >> 20, t2 = p2 >> 20, t3 = p3 >> 20;
        c0 += (t0 == 0) + (t1 == 0) + (t2 == 0) + (t3 == 0);
        c1 += (t0 == 1) + (t1 == 1) + (t2 == 1) + (t3 == 1);
        c2 += (t0 == 2) + (t1 == 2) + (t2 == 2) + (t3 == 2);
    }
    for (; e < end; ++e) {
        int p = packed[e];
        s0 += bfu(xb[(p & 0xFFFFF) * EMB + lane]);
        int t = p >> 20;
        c0 += (t == 0); c1 += (t == 1); c2 += (t == 2);
    }
    float inv = 1.0f / (float)max(end - beg, 1);
    aggx[node * EMB + lane] = f2bf((s0 + s1 + s2 + s3) * inv);
    if (lane == 0)
        *(float4*)&fc[node * 4] = make_float4(c0 * inv, c1 * inv, c2 * inv, 0.f);
}

// gather: mean of h[src] (128 bf16 = 64 dwords). One wave per node, unroll 2 edges.
__global__ __launch_bounds__(256) void k_agg2(
    const int* __restrict__ offsets, const int* __restrict__ packed,
    const u32* __restrict__ hb, u32* __restrict__ aggh) {
    int node = (blockIdx.x * 256 + threadIdx.x) >> 6;
    int lane = threadIdx.x & 63;
    int beg = offsets[node], end = offsets[node + 1];
    float a0 = 0.f, a1 = 0.f, b0 = 0.f, b1 = 0.f;
    int e = beg;
    for (; e + 2 <= end; e += 2) {
        u32 u = hb[(packed[e] & 0xFFFFF) * 64 + lane];
        u32 v = hb[(packed[e + 1] & 0xFFFFF) * 64 + lane];
        a0 += __uint_as_float(u << 16);
        a1 += __uint_as_float(u & 0xFFFF0000u);
        b0 += __uint_as_float(v << 16);
        b1 += __uint_as_float(v & 0xFFFF0000u);
    }
    if (e < end) {
        u32 u = hb[(packed[e] & 0xFFFFF) * 64 + lane];
        a0 += __uint_as_float(u << 16);
        a1 += __uint_as_float(u & 0xFFFF0000u);
    }
    float inv = 1.0f / (float)max(end - beg, 1);
    aggh[node * 64 + lane] = (u32)f2bf((a0 + b0) * inv) | ((u32)f2bf((a1 + b1) * inv) << 16);
}

// MFMA GEMM layer1: M=128/block (512 thr, 8 waves), K=128, B in swizzled LDS.
// wave (wm 0..3, wn 0..1): rows wm*32..+32, cols wn*64..+64
__global__ __launch_bounds__(512) void k_gemm1(
    const u16* __restrict__ aggx, const u16* __restrict__ xb,
    const float* __restrict__ fc, const u16* __restrict__ Bt1,
    const float* __restrict__ b1, const float* __restrict__ relp,
    u16* __restrict__ h) {
    __shared__ u16 Bs[128 * 128];   // 32KB; slot p holds canonical chunk p^(col&7)
    int tid = threadIdx.x;
    for (int i = tid; i < 2048; i += 512) {
        int col = i >> 4, p = i & 15;
        ((short8*)Bs)[i] = *(const short8*)(Bt1 + col * 128 + ((p ^ (col & 7)) << 3));
    }
    int lane = tid & 63, w = tid >> 6;
    int wm = w >> 1, wn = w & 1;
    int mbase = blockIdx.x * 128 + wm * 32;
    int ra = min(mbase + (lane & 15), NN - 1);
    int rb = min(mbase + 16 + (lane & 15), NN - 1);
    int kg = (lane >> 4) * 8;
    f32x4 acc[2][4] = {};
    __syncthreads();
    #pragma unroll
    for (int step = 0; step < 4; ++step) {
        int kk = step * 32 + kg;
        const u16* pa = (step < 2) ? (aggx + ra * EMB + kk) : (xb + ra * EMB + kk - 64);
        const u16* pb = (step < 2) ? (aggx + rb * EMB + kk) : (xb + rb * EMB + kk - 64);
        short8 a0 = *(const short8*)pa;
        short8 a1 = *(const short8*)pb;
        int c = step * 4 + (lane >> 4);
        #pragma unroll
        for (int nf = 0; nf < 4; ++nf) {
            int col = wn * 64 + nf * 16 + (lane & 15);
            short8 b = *(const short8*)&Bs[col * 128 + ((c ^ (col & 7)) << 3)];
            acc[0][nf] = __builtin_amdgcn_mfma_f32_16x16x32_bf16(a0, b, acc[0][nf], 0, 0, 0);
            acc[1][nf] = __builtin_amdgcn_mfma_f32_16x16x32_bf16(a1, b, acc[1][nf], 0, 0, 0);
        }
    }
    float eb[4], e0[4], e1[4], e2[4];
    #pragma unroll
    for (int nf = 0; nf < 4; ++nf) {
        int cc = wn * 64 + nf * 16 + (lane & 15);
        eb[nf] = b1[cc]; e0[nf] = relp[cc]; e1[nf] = relp[128 + cc]; e2[nf] = relp[256 + cc];
    }
    #pragma unroll
    for (int mi = 0; mi < 2; ++mi) {
        #pragma unroll
        for (int reg = 0; reg < 4; ++reg) {
            int row = mbase + mi * 16 + (lane >> 4) * 4 + reg;
            if (row >= NN) continue;
            float4 f = *(const float4*)&fc[row * 4];
            #pragma unroll
            for (int nf = 0; nf < 4; ++nf) {
                int cc = wn * 64 + nf * 16 + (lane & 15);
                float v = acc[mi][nf][reg] + eb[nf] + f.x * e0[nf] + f.y * e1[nf] + f.z * e2[nf];
                h[row * HID + cc] = f2bf(fmaxf(v, 0.f));
            }
        }
    }
}

// MFMA GEMM layer2: M=128/block (512 thr), K=256, B in swizzled LDS; pooled atomicMax
__global__ __launch_bounds__(512) void k_gemm2(
    const u16* __restrict__ aggh, const u16* __restrict__ h,
    const u16* __restrict__ Bt2, const float* __restrict__ b2,
    const int* __restrict__ batch, unsigned* __restrict__ genc) {
    __shared__ u16 Bs[128 * 256];   // 64KB
    int tid = threadIdx.x;
    for (int i = tid; i < 4096; i += 512) {
        int col = i >> 5, p = i & 31;
        ((short8*)Bs)[i] = *(const short8*)(Bt2 + col * 256 + ((p ^ (col & 7)) << 3));
    }
    int lane = tid & 63, w = tid >> 6;
    int wm = w >> 1, wn = w & 1;
    int mbase = blockIdx.x * 128 + wm * 32;
    int ra = min(mbase + (lane & 15), NN - 1);
    int rb = min(mbase + 16 + (lane & 15), NN - 1);
    int kg = (lane >> 4) * 8;
    f32x4 acc[2][4] = {};
    __syncthreads();
    #pragma unroll
    for (int step = 0; step < 8; ++step) {
        int kk = step * 32 + kg;
        const u16* pa = (step < 4) ? (aggh + ra * HID + kk) : (h + ra * HID + kk - 128);
        const u16* pb = (step < 4) ? (aggh + rb * HID + kk) : (h + rb * HID + kk - 128);
        short8 a0 = *(const short8*)pa;
        short8 a1 = *(const short8*)pb;
        int c = step * 4 + (lane >> 4);
        #pragma unroll
        for (int nf = 0; nf < 4; ++nf) {
            int col = wn * 64 + nf * 16 + (lane & 15);
            short8 b = *(const short8*)&Bs[col * 256 + ((c ^ (col & 7)) << 3)];
            acc[0][nf] = __builtin_amdgcn_mfma_f32_16x16x32_bf16(a0, b, acc[0][nf], 0, 0, 0);
            acc[1][nf] = __builtin_amdgcn_mfma_f32_16x16x32_bf16(a1, b, acc[1][nf], 0, 0, 0);
        }
    }
    float bv[4];
    #pragma unroll
    for (int nf = 0; nf < 4; ++nf) bv[nf] = b2[wn * 64 + nf * 16 + (lane & 15)];
    #pragma unroll
    for (int mi = 0; mi < 2; ++mi) {
        int r0 = mbase + mi * 16 + (lane >> 4) * 4;
        if (r0 >= NN) continue;
        if (r0 + 3 < NN && batch[r0] == batch[r0 + 3]) {
            int bt = batch[r0];
            #pragma unroll
            for (int nf = 0; nf < 4; ++nf) {
                int cc = wn * 64 + nf * 16 + (lane & 15);
                f32x4 a = acc[mi][nf];
                float v = fmaxf(fmaxf(a[0], a[1]), fmaxf(a[2], a[3])) + bv[nf];
                atomicMax(&genc[bt * HID + cc], fenc(v));
            }
        } else {
            #pragma unroll
            for (int reg = 0; reg < 4; ++reg) {
                int row = r0 + reg;
                if (row >= NN) continue;
                int bt = batch[row];
                #pragma unroll
                for (int nf = 0; nf < 4; ++nf) {
                    int cc = wn * 64 + nf * 16 + (lane & 15);
                    atomicMax(&genc[bt * HID + cc], fenc(acc[mi][nf][reg] + bv[nf]));
                }
            }
        }
    }
}

__global__ void k_final(const unsigned* __restrict__ genc,
                        const float* __restrict__ lin_w, const float* __restrict__ lin_b,
                        float* __restrict__ out) {
    int gr = blockIdx.x;
    int lane = threadIdx.x;  // 64
    float g0 = fmaxf(fdec(genc[gr * HID + lane]), 0.f);
    float g1 = fmaxf(fdec(genc[gr * HID + 64 + lane]), 0.f);
    #pragma unroll
    for (int c = 0; c < NCLS; ++c) {
        float p = g0 * lin_w[lane * NCLS + c] + g1 * lin_w[(lane + 64) * NCLS + c];
        for (int off = 32; off > 0; off >>= 1)
            p += __shfl_down(p, off, 64);
        if (lane == 0) out[gr * NCLS + c] = p + lin_b[c];
    }
}

extern "C" void kernel_launch(void* const* d_in, const int* in_sizes, int n_in,
                              void* d_out, int out_size, void* d_ws, size_t ws_size,
                              hipStream_t stream) {
    const int* x_tokens   = (const int*)d_in[0];
    const int* edge_index = (const int*)d_in[1];
    const int* edge_type  = (const int*)d_in[2];
    const int* batch      = (const int*)d_in[3];
    const float* emb_table = (const float*)d_in[5];
    const float* rel_table = (const float*)d_in[6];
    const float* w1_l = (const float*)d_in[7];
    const float* b1   = (const float*)d_in[8];
    const float* w1_r = (const float*)d_in[9];
    const float* w2_l = (const float*)d_in[10];
    const float* b2   = (const float*)d_in[11];
    const float* w2_r = (const float*)d_in[12];
    const float* lin_w = (const float*)d_in[13];
    const float* lin_b = (const float*)d_in[14];
    float* out = (float*)d_out;

    const int* src = edge_index;
    const int* dst = edge_index + NE;

    char* ws = (char*)d_ws;
    size_t off = 0;
    auto alloc = [&](size_t bytes) {
        void* p = ws + off;
        off = (off + bytes + 255) & ~(size_t)255;
        return p;
    };
    u16* xb      = (u16*)alloc((size_t)NN * EMB * 2);
    u16* aggx    = (u16*)alloc((size_t)NN * EMB * 2);
    u16* h       = (u16*)alloc((size_t)NN * HID * 2);
    u16* aggh    = (u16*)alloc((size_t)NN * HID * 2);
    float* fc    = (float*)alloc((size_t)NN * 4 * 4);
    int* offsets = (int*)alloc((size_t)(NN + 1) * 4);
    int* packed  = (int*)alloc((size_t)NE * 4);
    u32* coarse  = (u32*)alloc((size_t)NE * 4);
    int* counts  = (int*)alloc((size_t)NSCAN * 4);
    int* scanned = (int*)alloc((size_t)NSCAN * 4);
    int* gpart   = (int*)alloc((size_t)128 * 4);
    unsigned* genc = (unsigned*)alloc((size_t)NG * HID * 4);
    float* relp  = (float*)alloc((size_t)3 * HID * 4);
    u16* Bt1     = (u16*)alloc((size_t)128 * 128 * 2);
    u16* Bt2     = (u16*)alloc((size_t)128 * 256 * 2);
    (void)ws_size; (void)in_sizes; (void)n_in; (void)out_size;

    const int MT = (NN + 127) / 128;  // 782 GEMM m-tiles

    hipLaunchKernelGGL(k_init,  dim3(1000), dim3(256), 0, stream,
                       genc, relp, Bt1, Bt2, rel_table, w1_l, w1_r, w2_l, w2_r);
    hipLaunchKernelGGL(k_embed, dim3(NN * 32 / 256), dim3(256), 0, stream,
                       x_tokens, emb_table, (u32*)xb);
    hipLaunchKernelGGL(k_cnt,   dim3(NBA), dim3(256), 0, stream, dst, counts);
    hipLaunchKernelGGL(k_gs1,   dim3(GS_NB), dim3(256), 0, stream, counts, gpart);
    hipLaunchKernelGGL(k_gs2,   dim3(1), dim3(128), 0, stream, gpart);
    hipLaunchKernelGGL(k_gs3,   dim3(GS_NB), dim3(256), 0, stream, counts, gpart, scanned);
    hipLaunchKernelGGL(k_part,  dim3(NBA), dim3(256), 0, stream,
                       src, dst, edge_type, scanned, coarse);
    hipLaunchKernelGGL(k_csr,   dim3(NBKT), dim3(256), 0, stream,
                       scanned, coarse, offsets, packed);
    hipLaunchKernelGGL(k_agg1,  dim3(NN / 4), dim3(256), 0, stream,
                       offsets, packed, xb, aggx, fc);
    hipLaunchKernelGGL(k_gemm1, dim3(MT), dim3(512), 0, stream,
                       aggx, xb, fc, Bt1, b1, relp, h);
    hipLaunchKernelGGL(k_agg2,  dim3(NN / 4), dim3(256), 0, stream,
                       offsets, packed, (const u32*)h, (u32*)aggh);
    hipLaunchKernelGGL(k_gemm2, dim3(MT), dim3(512), 0, stream,
                       aggh, h, Bt2, b2, batch, genc);
    hipLaunchKernelGGL(k_final, dim3(NG), dim3(64), 0, stream, genc, lin_w, lin_b, out);
}